// Round 1
// 163.765 us; speedup vs baseline: 1.0416x; 1.0416x over previous
//
#include <hip/hip_runtime.h>

#define TT 1024
#define CC 128
#define LL 128
#define EPSF 1e-7f
#define LN2F 0.69314718055994531f

#define LOG2F(x) __builtin_amdgcn_logf(x)

typedef unsigned int uint;

template <int CTRL>
__device__ __forceinline__ int dpp_i(int old_, int x) {
  return __builtin_amdgcn_update_dpp(old_, x, CTRL, 0xf, 0xf, false);
}
// shift a3 to next lane (wave_shr:1); lane 0 receives 0.0f via bound_ctrl
__device__ __forceinline__ float dpp_shr1_f32(float x) {
  return __uint_as_float((uint)__builtin_amdgcn_update_dpp(
      0, (int)__float_as_uint(x), 0x138, 0xf, 0xf, true));
}

// fp32 -> bf16 bits, round-to-nearest-even (inputs finite positive)
__device__ __forceinline__ uint bf16bits(float x) {
  uint u = __float_as_uint(x);
  return (u + 0x7fffu + ((u >> 16) & 1u)) >> 16;
}

// ---- prep (parallel): normalized emission probs, transposed for the scan ----
// Block = 512 threads = 8 waves; block handles (b, 8 consecutive t).
//   ET[b][t4][L] (uint4 over t in group-of-4: bf16 p[lab 2L] | p[lab 2L+1])
//   EB[b][t] (fp32 blank prob)
__global__ __launch_bounds__(512) void prep_kernel(const int* __restrict__ yt,
                                                   const float* __restrict__ yp,
                                                   uint* __restrict__ ET,
                                                   float* __restrict__ EB) {
  const int tid = threadIdx.x;
  const int w = tid >> 6;  // wave 0..7
  const int L = tid & 63;
  const int b = blockIdx.x >> 7;
  const int tg = blockIdx.x & 127;
  const int t = tg * 8 + w;

  __shared__ float rowp[8][130];  // normalized probs per wave-row
  __shared__ uint tp[64][9];      // [L][w] transpose buffer (+1 pad)

  const float* P = yp + ((size_t)b * TT + t) * CC;
  const float2 v = *(const float2*)(P + 2 * L);
  float x = (v.x + EPSF) + (v.y + EPSF);
#pragma unroll
  for (int off = 32; off > 0; off >>= 1) x += __shfl_xor(x, off);
  const float r = 1.0f / x;
  const float er = EPSF * r;
  *(float2*)&rowp[w][2 * L] =
      make_float2(__builtin_fmaf(v.x, r, er), __builtin_fmaf(v.y, r, er));
  const int2 lab = *(const int2*)(yt + b * LL + 2 * L);
  if (L == 63) EB[b * TT + t] = __builtin_fmaf(v.y, r, er);  // c=127 blank
  __syncthreads();
  const float p1 = rowp[w][lab.x];
  const float p2 = rowp[w][lab.y];
  tp[L][w] = (bf16bits(p2) << 16) | bf16bits(p1);
  __syncthreads();
  if (tid < 128) {  // 2 t4-groups x 64 lanes, coalesced uint4 stores
    const int g4 = tid >> 6, Lo = tid & 63;
    uint4 val;
    val.x = tp[Lo][g4 * 4 + 0];
    val.y = tp[Lo][g4 * 4 + 1];
    val.z = tp[Lo][g4 * 4 + 2];
    val.w = tp[Lo][g4 * 4 + 3];
    ((uint4*)ET)[((size_t)(b * 256 + tg * 2 + g4) << 6) + Lo] = val;
  }
}

// ---- serial scan: fp32 linear-domain scaled forward, one wave per b ----
// Lane L owns states 4L..4L+3 (lane63's extra a4 is state 256). alpha_true =
// a * 2^ell, wave-uniform ell. fp32 range management: the scaled alpha max is
// pinned near 2^100 (init a0 = 2^100, ell = -100; rescale-to-2^100 every 16
// steps). Worst realistic per-16-step drop ~120 bits keeps the max far above
// the 2^-126 normal floor; states >100 bits below the max flush to 0 and are
// numerically irrelevant to the final log-sum. Probs are >= eps/sum ~ 2^-29,
// bounding even adversarial single-step drops. The 32-step emission ring
// stays in 16 NAMED uint4/float4 variables (arrays demote to scratch).

// one lattice step using word wv (bf16 pair) and blank prob pbf
#define CTC_STEP(wv, pbf)                                   \
  do {                                                      \
    const float p1 = __uint_as_float((wv) << 16);           \
    const float p2 = __uint_as_float((wv) & 0xffff0000u);   \
    const float pb = (pbf);                                 \
    const float p3 = dpp_shr1_f32(a3);                      \
    const float n0 = (a0 + p3) * pb;                        \
    const float n1 = __builtin_fmaf(s1f, p3, a0 + a1) * p1; \
    const float n2 = (a2 + a1) * pb;                        \
    const float n3 = __builtin_fmaf(s3f, a1, a3 + a2) * p2; \
    const float n4 = (a4 + a3) * pb;                        \
    a0 = n0; a1 = n1; a2 = n2; a3 = n3; a4 = n4;            \
  } while (0)

#define CTC_GROUP(g)                        \
  do {                                      \
    CTC_STEP(et##g.x, eb##g.x);             \
    CTC_STEP(et##g.y, eb##g.y);             \
    CTC_STEP(et##g.z, eb##g.z);             \
    CTC_STEP(et##g.w, eb##g.w);             \
    const int t4n = min(tb4 + 8 + g, 255);  \
    et##g = Et[(size_t)t4n * 64];           \
    eb##g = *(const float4*)(Bp + t4n * 4); \
  } while (0)

// rescale wave-max exponent back to 2^100 (biased 227); e clamped so the
// correction factor stays a normal fp32 even after a catastrophic window
#define CTC_RESCALE()                                                \
  do {                                                               \
    const float m = fmaxf(fmaxf(fmaxf(a0, a1), fmaxf(a2, a3)), a4);  \
    int ke = (int)(__float_as_uint(m) >> 23);                        \
    ke = max(ke, dpp_i<0x111>(ke, ke));                              \
    ke = max(ke, dpp_i<0x112>(ke, ke));                              \
    ke = max(ke, dpp_i<0x114>(ke, ke));                              \
    ke = max(ke, dpp_i<0x118>(ke, ke));                              \
    ke = max(ke, dpp_i<0x142>(ke, ke));                              \
    ke = max(ke, dpp_i<0x143>(ke, ke));                              \
    ke = __builtin_amdgcn_readlane(ke, 63);                          \
    int e = ke - 227; /* biased_exp(max) - (127 + 100) */            \
    e = e < -127 ? -127 : e;                                         \
    const float sc = __uint_as_float((uint)(127 - e) << 23);         \
    a0 *= sc; a1 *= sc; a2 *= sc; a3 *= sc; a4 *= sc;                \
    ell += e;                                                        \
  } while (0)

__global__ __launch_bounds__(64) void scan_kernel(const int* __restrict__ yt,
                                                  const uint* __restrict__ ET,
                                                  const float* __restrict__ EB,
                                                  float* __restrict__ out) {
  const int b = blockIdx.x;
  const int L = threadIdx.x & 63;

  const int2 lab = *(const int2*)(yt + b * LL + 2 * L);
  const int labm1 = __shfl_up(lab.y, 1);
  const float s1f = ((L > 0) && (lab.x != labm1)) ? 1.0f : 0.0f;  // s=4L+1
  const float s3f = (lab.y != lab.x) ? 1.0f : 0.0f;               // s=4L+3

  const uint4* Et = (const uint4*)ET + ((size_t)b << 14) + L;  // [t4][64]
  const float* Bp = EB + b * TT;

  uint4 et0 = Et[0 * 64], et1 = Et[1 * 64], et2 = Et[2 * 64], et3 = Et[3 * 64];
  uint4 et4 = Et[4 * 64], et5 = Et[5 * 64], et6 = Et[6 * 64], et7 = Et[7 * 64];
  float4 eb0 = *(const float4*)(Bp + 0), eb1 = *(const float4*)(Bp + 4);
  float4 eb2 = *(const float4*)(Bp + 8), eb3 = *(const float4*)(Bp + 12);
  float4 eb4 = *(const float4*)(Bp + 16), eb5 = *(const float4*)(Bp + 20);
  float4 eb6 = *(const float4*)(Bp + 24), eb7 = *(const float4*)(Bp + 28);

  // virtual alpha_{-1}: state 0 = 2^100, rest 0; first step yields alpha_0
  float a0 = (L == 0) ? 0x1.0p100f : 0.0f;
  float a1 = 0.0f, a2 = 0.0f, a3 = 0.0f, a4 = 0.0f;
  int ell = -100;  // wave-uniform: alpha_true = a * 2^ell

#pragma unroll 1
  for (int tb4 = 0; tb4 < TT / 4; tb4 += 8) {
    CTC_GROUP(0);
    CTC_GROUP(1);
    CTC_GROUP(2);
    CTC_GROUP(3);
    CTC_RESCALE();
    CTC_GROUP(4);
    CTC_GROUP(5);
    CTC_GROUP(6);
    CTC_GROUP(7);
    CTC_RESCALE();
  }

  if (L == 63) {
    // states 255 (=a3), 256 (=a4): loglik = ln2 * (ell + log2(a3+a4))
    float s = a3 + a4;
    if (s < 1e-37f) s = 1e-37f;  // stay normal; loud-but-finite floor
    out[b] = -LN2F * ((float)ell + LOG2F(s));
  }
}

extern "C" void kernel_launch(void* const* d_in, const int* in_sizes, int n_in,
                              void* d_out, int out_size, void* d_ws,
                              size_t ws_size, hipStream_t stream) {
  const int* yt = (const int*)d_in[0];
  const float* yp = (const float*)d_in[1];
  float* out = (float*)d_out;
  const int B = in_sizes[0] / LL;  // 128
  uint* ET = (uint*)d_ws;                                       // 33.55 MB
  float* EB = (float*)((char*)d_ws + (size_t)B * 64 * TT * 4);  // +512 KB
  hipLaunchKernelGGL(prep_kernel, dim3(B * 128), dim3(512), 0, stream, yt, yp,
                     ET, EB);
  hipLaunchKernelGGL(scan_kernel, dim3(B), dim3(64), 0, stream, yt, ET, EB,
                     out);
}

// Round 2
// 152.723 us; speedup vs baseline: 1.1170x; 1.0723x over previous
//
#include <hip/hip_runtime.h>

#define TT 1024
#define CC 128
#define LL 128
#define EPSF 1e-7f
#define LN2F 0.69314718055994531f

#define LOG2F(x) __builtin_amdgcn_logf(x)

typedef unsigned int uint;

template <int CTRL>
__device__ __forceinline__ int dpp_i(int old_, int x) {
  return __builtin_amdgcn_update_dpp(old_, x, CTRL, 0xf, 0xf, false);
}
// shift a3 to next lane (wave_shr:1); lane 0 receives 0.0f via bound_ctrl
__device__ __forceinline__ float dpp_shr1_f32(float x) {
  return __uint_as_float((uint)__builtin_amdgcn_update_dpp(
      0, (int)__float_as_uint(x), 0x138, 0xf, 0xf, true));
}

// fp32 -> bf16 bits, round-to-nearest-even (inputs finite positive)
__device__ __forceinline__ uint bf16bits(float x) {
  uint u = __float_as_uint(x);
  return (u + 0x7fffu + ((u >> 16) & 1u)) >> 16;
}

// async global->LDS, 16B per lane: LDS dest = base + lane*16 (wave-uniform
// base), global src = per-lane address. vmcnt-counted, zero VGPR cost.
#define GL16(gp, lp)                                            \
  __builtin_amdgcn_global_load_lds(                             \
      (const __attribute__((address_space(1))) void*)(gp),      \
      (__attribute__((address_space(3))) void*)(lp), 16, 0, 0)

// ---- prep (parallel): normalized emission probs, transposed for the scan ----
// Block = 512 threads = 8 waves; block handles (b, 8 consecutive t).
//   ET[b][t4][L] (uint4 over t in group-of-4: bf16 p[lab 2L] | p[lab 2L+1])
//   EB[b][t] (fp32 blank prob)
__global__ __launch_bounds__(512) void prep_kernel(const int* __restrict__ yt,
                                                   const float* __restrict__ yp,
                                                   uint* __restrict__ ET,
                                                   float* __restrict__ EB) {
  const int tid = threadIdx.x;
  const int w = tid >> 6;  // wave 0..7
  const int L = tid & 63;
  const int b = blockIdx.x >> 7;
  const int tg = blockIdx.x & 127;
  const int t = tg * 8 + w;

  __shared__ float rowp[8][130];  // normalized probs per wave-row
  __shared__ uint tp[64][9];      // [L][w] transpose buffer (+1 pad)

  const float* P = yp + ((size_t)b * TT + t) * CC;
  const float2 v = *(const float2*)(P + 2 * L);
  float x = (v.x + EPSF) + (v.y + EPSF);
#pragma unroll
  for (int off = 32; off > 0; off >>= 1) x += __shfl_xor(x, off);
  const float r = 1.0f / x;
  const float er = EPSF * r;
  *(float2*)&rowp[w][2 * L] =
      make_float2(__builtin_fmaf(v.x, r, er), __builtin_fmaf(v.y, r, er));
  const int2 lab = *(const int2*)(yt + b * LL + 2 * L);
  if (L == 63) EB[b * TT + t] = __builtin_fmaf(v.y, r, er);  // c=127 blank
  __syncthreads();
  const float p1 = rowp[w][lab.x];
  const float p2 = rowp[w][lab.y];
  tp[L][w] = (bf16bits(p2) << 16) | bf16bits(p1);
  __syncthreads();
  if (tid < 128) {  // 2 t4-groups x 64 lanes, coalesced uint4 stores
    const int g4 = tid >> 6, Lo = tid & 63;
    uint4 val;
    val.x = tp[Lo][g4 * 4 + 0];
    val.y = tp[Lo][g4 * 4 + 1];
    val.z = tp[Lo][g4 * 4 + 2];
    val.w = tp[Lo][g4 * 4 + 3];
    ((uint4*)ET)[((size_t)(b * 256 + tg * 2 + g4) << 6) + Lo] = val;
  }
}

// ---- serial scan: fp32 linear-domain scaled forward, one wave per b ----
// Lane L owns states 4L..4L+3 (lane63's extra a4 is state 256). alpha_true =
// a * 2^ell, wave-uniform ell; max pinned near 2^100, rescale every 16 steps.
//
// Memory: round-1's 16-register-uint4 ring could not be register-resident
// (VGPR_Count=40 < 64-reg ring) -> only ~8 loads in flight -> the wave was
// HBM-latency throttled (~124 cy/step ~ 900cy/8 loads per 4-step group).
// Now ET is staged through a 4-buffer LDS ring via global_load_lds (no VGPR
// cost), prefetched 2 iterations (16 KB) ahead with counted vmcnt(8) waits
// (never 0), and consumed with ds_read_b128 one group ahead into alternating
// named registers. EB (4 KB) is loaded to LDS once in the prologue.

// one lattice step using word wv (bf16 pair) and blank prob pbf
#define CTC_STEP(wv, pbf)                                   \
  do {                                                      \
    const float p1 = __uint_as_float((wv) << 16);           \
    const float p2 = __uint_as_float((wv) & 0xffff0000u);   \
    const float pb = (pbf);                                 \
    const float p3 = dpp_shr1_f32(a3);                      \
    const float n0 = (a0 + p3) * pb;                        \
    const float n1 = __builtin_fmaf(s1f, p3, a0 + a1) * p1; \
    const float n2 = (a2 + a1) * pb;                        \
    const float n3 = __builtin_fmaf(s3f, a1, a3 + a2) * p2; \
    const float n4 = (a4 + a3) * pb;                        \
    a0 = n0; a1 = n1; a2 = n2; a3 = n3; a4 = n4;            \
  } while (0)

#define CTC_QUAD(et, eb) \
  do {                   \
    CTC_STEP(et.x, eb.x); \
    CTC_STEP(et.y, eb.y); \
    CTC_STEP(et.z, eb.z); \
    CTC_STEP(et.w, eb.w); \
  } while (0)

// rescale wave-max exponent back to 2^100 (biased 227); e clamped so the
// correction factor stays a normal fp32 even after a catastrophic window
#define CTC_RESCALE()                                                \
  do {                                                               \
    const float m = fmaxf(fmaxf(fmaxf(a0, a1), fmaxf(a2, a3)), a4);  \
    int ke = (int)(__float_as_uint(m) >> 23);                        \
    ke = max(ke, dpp_i<0x111>(ke, ke));                              \
    ke = max(ke, dpp_i<0x112>(ke, ke));                              \
    ke = max(ke, dpp_i<0x114>(ke, ke));                              \
    ke = max(ke, dpp_i<0x118>(ke, ke));                              \
    ke = max(ke, dpp_i<0x142>(ke, ke));                              \
    ke = max(ke, dpp_i<0x143>(ke, ke));                              \
    ke = __builtin_amdgcn_readlane(ke, 63);                          \
    int e = ke - 227; /* biased_exp(max) - (127 + 100) */            \
    e = e < -127 ? -127 : e;                                         \
    const float sc = __uint_as_float((uint)(127 - e) << 23);         \
    a0 *= sc; a1 *= sc; a2 *= sc; a3 *= sc; a4 *= sc;                \
    ell += e;                                                        \
  } while (0)

__global__ __launch_bounds__(64) void scan_kernel(const int* __restrict__ yt,
                                                  const uint* __restrict__ ET,
                                                  const float* __restrict__ EB,
                                                  float* __restrict__ out) {
  const int b = blockIdx.x;
  const int L = threadIdx.x & 63;

  __shared__ uint4 ETl[4][8][64];  // 32 KB: 4 iteration buffers
  __shared__ float4 EBl[256];      // 4 KB: all blank probs for this b

  const int2 lab = *(const int2*)(yt + b * LL + 2 * L);
  const int labm1 = __shfl_up(lab.y, 1);
  const float s1f = ((L > 0) && (lab.x != labm1)) ? 1.0f : 0.0f;  // s=4L+1
  const float s3f = (lab.y != lab.x) ? 1.0f : 0.0f;               // s=4L+3

  const uint4* Et = (const uint4*)ET + ((size_t)b << 14) + L;  // [t4][64]
  const float* Bp = EB + b * TT;

  // prologue: EB (4 issues) + iteration 0,1 ET tiles (8 issues each)
#pragma unroll
  for (int k = 0; k < 4; ++k)
    GL16(Bp + k * 256 + L * 4, (char*)EBl + k * 1024);
#pragma unroll
  for (int g = 0; g < 8; ++g) GL16(Et + g * 64, &ETl[0][g][0]);
#pragma unroll
  for (int g = 0; g < 8; ++g) GL16(Et + (8 + g) * 64, &ETl[1][g][0]);
  asm volatile("s_waitcnt vmcnt(8)" ::: "memory");  // EB + buf0 landed

  uint4 etA = ETl[0][0][L], etB;
  float4 ebA = EBl[0], ebB;

  // virtual alpha_{-1}: state 0 = 2^100, rest 0; first step yields alpha_0
  float a0 = (L == 0) ? 0x1.0p100f : 0.0f;
  float a1 = 0.0f, a2 = 0.0f, a3 = 0.0f, a4 = 0.0f;
  int ell = -100;  // wave-uniform: alpha_true = a * 2^ell

#pragma unroll 1
  for (int i = 0; i < 32; ++i) {
    {  // issue iteration i+2 tile into buffer (i+2)&3 (clamped dup at tail)
      const int ip = (i + 2 < 32) ? (i + 2) : 31;
      const uint4* src = Et + (size_t)ip * 512;
      uint4* dst = &ETl[(i + 2) & 3][0][0];
#pragma unroll
      for (int g = 0; g < 8; ++g) GL16(src + g * 64, dst + g * 64);
    }
    const uint4* cur = &ETl[i & 3][0][0];
    const int ebi = i * 8;
    etB = cur[1 * 64 + L]; ebB = EBl[ebi + 1];
    CTC_QUAD(etA, ebA);  // g0
    etA = cur[2 * 64 + L]; ebA = EBl[ebi + 2];
    CTC_QUAD(etB, ebB);  // g1
    etB = cur[3 * 64 + L]; ebB = EBl[ebi + 3];
    CTC_QUAD(etA, ebA);  // g2
    etA = cur[4 * 64 + L]; ebA = EBl[ebi + 4];
    CTC_QUAD(etB, ebB);  // g3
    CTC_RESCALE();
    etB = cur[5 * 64 + L]; ebB = EBl[ebi + 5];
    CTC_QUAD(etA, ebA);  // g4
    etA = cur[6 * 64 + L]; ebA = EBl[ebi + 6];
    CTC_QUAD(etB, ebB);  // g5
    etB = cur[7 * 64 + L]; ebB = EBl[ebi + 7];
    CTC_QUAD(etA, ebA);  // g6
    // buffer (i+1)'s 8 loads were issued one full iteration ago; 8 newer
    // (buffer i+2) may stay in flight — counted wait, never vmcnt(0)
    asm volatile("s_waitcnt vmcnt(8)" ::: "memory");
    {
      const int ni = (i + 1 < 32) ? (i + 1) : 31;
      etA = ETl[(i + 1) & 3][0][L];  // next-iter g0
      ebA = EBl[ni * 8];
    }
    CTC_QUAD(etB, ebB);  // g7
    CTC_RESCALE();
  }

  if (L == 63) {
    // states 255 (=a3), 256 (=a4): loglik = ln2 * (ell + log2(a3+a4))
    float s = a3 + a4;
    if (s < 1e-37f) s = 1e-37f;  // stay normal; loud-but-finite floor
    out[b] = -LN2F * ((float)ell + LOG2F(s));
  }
}

extern "C" void kernel_launch(void* const* d_in, const int* in_sizes, int n_in,
                              void* d_out, int out_size, void* d_ws,
                              size_t ws_size, hipStream_t stream) {
  const int* yt = (const int*)d_in[0];
  const float* yp = (const float*)d_in[1];
  float* out = (float*)d_out;
  const int B = in_sizes[0] / LL;  // 128
  uint* ET = (uint*)d_ws;                                       // 33.55 MB
  float* EB = (float*)((char*)d_ws + (size_t)B * 64 * TT * 4);  // +512 KB
  hipLaunchKernelGGL(prep_kernel, dim3(B * 128), dim3(512), 0, stream, yt, yp,
                     ET, EB);
  hipLaunchKernelGGL(scan_kernel, dim3(B), dim3(64), 0, stream, yt, ET, EB,
                     out);
}

// Round 3
// 151.295 us; speedup vs baseline: 1.1275x; 1.0094x over previous
//
#include <hip/hip_runtime.h>

#define TT 1024
#define CC 128
#define LL 128
#define EPSF 1e-7f
#define LN2F 0.69314718055994531f

#define LOG2F(x) __builtin_amdgcn_logf(x)

typedef unsigned int uint;
typedef uint uintx4 __attribute__((ext_vector_type(4)));
typedef float floatx4 __attribute__((ext_vector_type(4)));

template <int CTRL>
__device__ __forceinline__ int dpp_i(int old_, int x) {
  return __builtin_amdgcn_update_dpp(old_, x, CTRL, 0xf, 0xf, false);
}
// shift a3 to next lane (wave_shr:1); lane 0 receives 0.0f via bound_ctrl
__device__ __forceinline__ float dpp_shr1_f32(float x) {
  return __uint_as_float((uint)__builtin_amdgcn_update_dpp(
      0, (int)__float_as_uint(x), 0x138, 0xf, 0xf, true));
}

// fp32 -> bf16 bits, round-to-nearest-even (inputs finite positive)
__device__ __forceinline__ uint bf16bits(float x) {
  uint u = __float_as_uint(x);
  return (u + 0x7fffu + ((u >> 16) & 1u)) >> 16;
}

// ---- prep (parallel): normalized emission probs, transposed for the scan ----
// Block = 512 threads = 8 waves; block handles (b, 8 consecutive t).
//   ET[b][t4][L] (uint4 over t in group-of-4: bf16 p[lab 2L] | p[lab 2L+1])
//   EB[b][t] (fp32 blank prob)
__global__ __launch_bounds__(512) void prep_kernel(const int* __restrict__ yt,
                                                   const float* __restrict__ yp,
                                                   uint* __restrict__ ET,
                                                   float* __restrict__ EB) {
  const int tid = threadIdx.x;
  const int w = tid >> 6;  // wave 0..7
  const int L = tid & 63;
  const int b = blockIdx.x >> 7;
  const int tg = blockIdx.x & 127;
  const int t = tg * 8 + w;

  __shared__ float rowp[8][130];  // normalized probs per wave-row
  __shared__ uint tp[64][9];      // [L][w] transpose buffer (+1 pad)

  const float* P = yp + ((size_t)b * TT + t) * CC;
  const float2 v = *(const float2*)(P + 2 * L);
  float x = (v.x + EPSF) + (v.y + EPSF);
#pragma unroll
  for (int off = 32; off > 0; off >>= 1) x += __shfl_xor(x, off);
  const float r = 1.0f / x;
  const float er = EPSF * r;
  *(float2*)&rowp[w][2 * L] =
      make_float2(__builtin_fmaf(v.x, r, er), __builtin_fmaf(v.y, r, er));
  const int2 lab = *(const int2*)(yt + b * LL + 2 * L);
  if (L == 63) EB[b * TT + t] = __builtin_fmaf(v.y, r, er);  // c=127 blank
  __syncthreads();
  const float p1 = rowp[w][lab.x];
  const float p2 = rowp[w][lab.y];
  tp[L][w] = (bf16bits(p2) << 16) | bf16bits(p1);
  __syncthreads();
  if (tid < 128) {  // 2 t4-groups x 64 lanes, coalesced uint4 stores
    const int g4 = tid >> 6, Lo = tid & 63;
    uint4 val;
    val.x = tp[Lo][g4 * 4 + 0];
    val.y = tp[Lo][g4 * 4 + 1];
    val.z = tp[Lo][g4 * 4 + 2];
    val.w = tp[Lo][g4 * 4 + 3];
    ((uint4*)ET)[((size_t)(b * 256 + tg * 2 + g4) << 6) + Lo] = val;
  }
}

// ---- serial scan: fp32 linear-domain scaled forward, one wave per b ----
// Lane L owns states 4L..4L+3 (lane63's extra a4 is state 256). alpha_true =
// a * 2^ell, wave-uniform ell; max pinned near 2^100, rescale every 16 steps.
//
// Memory (round-2 post-mortem): LDS staging hid HBM latency but added a
// second hop — 16 ds_reads/iter with only ~128 cy lead vs ~120-150 cy LDS
// latency exposed ~2000 cy/iter of lgkmcnt stall (VALUBusy ~30% of SIMD).
// Now: NO LDS. Emission ring = 4 named register sets (A..D), each 4 et
// uint4 + 4 eb float4, filled by volatile inline-asm global_load_dwordx4
// (compiler cannot sink them — round-1's failure mode). Prefetch runs 2
// sets (~1250 cy) ahead of consumption; one counted s_waitcnt vmcnt(16)
// per 16-step sub-iteration (sets S+1,S+2 = 16 loads stay in flight,
// never drained). Destination registers are tied to the waitcnt asm so
// uses cannot hoist above it (guide rule #18). Zero lgkmcnt in the loop.

#define GLD(d, p)                                    \
  asm volatile("global_load_dwordx4 %0, %1, off"     \
               : "=&v"(d)                            \
               : "v"((unsigned long long)(p)))

// issue one set's 8 loads: 4 lane-indexed et + 4 wave-uniform eb
#define PREFETCH(S, st)                                        \
  do {                                                         \
    const uintx4* _ea = Et + (size_t)(st) * 256;               \
    const float* _eb = Bp + (st) * 16;                         \
    GLD(et##S##0, _ea + 0 * 64);                               \
    GLD(et##S##1, _ea + 1 * 64);                               \
    GLD(et##S##2, _ea + 2 * 64);                               \
    GLD(et##S##3, _ea + 3 * 64);                               \
    GLD(eb##S##0, _eb + 0);                                    \
    GLD(eb##S##1, _eb + 4);                                    \
    GLD(eb##S##2, _eb + 8);                                    \
    GLD(eb##S##3, _eb + 12);                                   \
  } while (0)

// counted wait: the 16 newer loads (next two sets) stay in flight; tying
// the consumed registers creates data deps so uses can't hoist past it
#define WAITTIE(S)                                                    \
  asm volatile("s_waitcnt vmcnt(16)"                                  \
               : "+v"(et##S##0), "+v"(et##S##1), "+v"(et##S##2),      \
                 "+v"(et##S##3), "+v"(eb##S##0), "+v"(eb##S##1),      \
                 "+v"(eb##S##2), "+v"(eb##S##3))

// one lattice step using word wv (bf16 pair) and blank prob pbf
#define CTC_STEP(wv, pbf)                                   \
  do {                                                      \
    const float p1 = __uint_as_float((wv) << 16);           \
    const float p2 = __uint_as_float((wv) & 0xffff0000u);   \
    const float pb = (pbf);                                 \
    const float p3 = dpp_shr1_f32(a3);                      \
    const float n0 = (a0 + p3) * pb;                        \
    const float n1 = __builtin_fmaf(s1f, p3, a0 + a1) * p1; \
    const float n2 = (a2 + a1) * pb;                        \
    const float n3 = __builtin_fmaf(s3f, a1, a3 + a2) * p2; \
    const float n4 = (a4 + a3) * pb;                        \
    a0 = n0; a1 = n1; a2 = n2; a3 = n3; a4 = n4;            \
  } while (0)

#define CTC_QUAD(et, eb)          \
  do {                            \
    CTC_STEP((et)[0], (eb)[0]);   \
    CTC_STEP((et)[1], (eb)[1]);   \
    CTC_STEP((et)[2], (eb)[2]);   \
    CTC_STEP((et)[3], (eb)[3]);   \
  } while (0)

// rescale wave-max exponent back to 2^100 (biased 227); e clamped so the
// correction factor stays a normal fp32 even after a catastrophic window
#define CTC_RESCALE()                                                \
  do {                                                               \
    const float m = fmaxf(fmaxf(fmaxf(a0, a1), fmaxf(a2, a3)), a4);  \
    int ke = (int)(__float_as_uint(m) >> 23);                        \
    ke = max(ke, dpp_i<0x111>(ke, ke));                              \
    ke = max(ke, dpp_i<0x112>(ke, ke));                              \
    ke = max(ke, dpp_i<0x114>(ke, ke));                              \
    ke = max(ke, dpp_i<0x118>(ke, ke));                              \
    ke = max(ke, dpp_i<0x142>(ke, ke));                              \
    ke = max(ke, dpp_i<0x143>(ke, ke));                              \
    ke = __builtin_amdgcn_readlane(ke, 63);                          \
    int e = ke - 227; /* biased_exp(max) - (127 + 100) */            \
    e = e < -127 ? -127 : e;                                         \
    const float sc = __uint_as_float((uint)(127 - e) << 23);         \
    a0 *= sc; a1 *= sc; a2 *= sc; a3 *= sc; a4 *= sc;                \
    ell += e;                                                        \
  } while (0)

// 16-step sub-iteration on set S (4 quads + 1 rescale)
#define COMPUTE(S)                    \
  do {                                \
    CTC_QUAD(et##S##0, eb##S##0);     \
    CTC_QUAD(et##S##1, eb##S##1);     \
    CTC_QUAD(et##S##2, eb##S##2);     \
    CTC_QUAD(et##S##3, eb##S##3);     \
    CTC_RESCALE();                    \
  } while (0)

__global__ __launch_bounds__(64) void scan_kernel(const int* __restrict__ yt,
                                                  const uint* __restrict__ ET,
                                                  const float* __restrict__ EB,
                                                  float* __restrict__ out) {
  const int b = blockIdx.x;
  const int L = threadIdx.x & 63;

  const int2 lab = *(const int2*)(yt + b * LL + 2 * L);
  const int labm1 = __shfl_up(lab.y, 1);
  const float s1f = ((L > 0) && (lab.x != labm1)) ? 1.0f : 0.0f;  // s=4L+1
  const float s3f = (lab.y != lab.x) ? 1.0f : 0.0f;               // s=4L+3

  const uintx4* Et = (const uintx4*)ET + ((size_t)b << 14) + L;  // [t4][64]
  const float* Bp = EB + b * TT;

  uintx4 etA0, etA1, etA2, etA3, etB0, etB1, etB2, etB3;
  uintx4 etC0, etC1, etC2, etC3, etD0, etD1, etD2, etD3;
  floatx4 ebA0, ebA1, ebA2, ebA3, ebB0, ebB1, ebB2, ebB3;
  floatx4 ebC0, ebC1, ebC2, ebC3, ebD0, ebD1, ebD2, ebD3;

  // prologue: sets A (sub-iter 0) and B (sub-iter 1)
  PREFETCH(A, 0);
  PREFETCH(B, 1);

  // virtual alpha_{-1}: state 0 = 2^100, rest 0; first step yields alpha_0
  float a0 = (L == 0) ? 0x1.0p100f : 0.0f;
  float a1 = 0.0f, a2 = 0.0f, a3 = 0.0f, a4 = 0.0f;
  int ell = -100;  // wave-uniform: alpha_true = a * 2^ell

  // 64 sub-iterations of 16 steps; 4-set rotation, prefetch 2 ahead
#pragma unroll 1
  for (int kk = 0; kk < 16; ++kk) {
    const int st = kk * 4;
    PREFETCH(C, st + 2);
    WAITTIE(A);
    COMPUTE(A);
    PREFETCH(D, st + 3);
    WAITTIE(B);
    COMPUTE(B);
    PREFETCH(A, min(st + 4, 63));
    WAITTIE(C);
    COMPUTE(C);
    PREFETCH(B, min(st + 5, 63));
    WAITTIE(D);
    COMPUTE(D);
  }

  if (L == 63) {
    // states 255 (=a3), 256 (=a4): loglik = ln2 * (ell + log2(a3+a4))
    float s = a3 + a4;
    if (s < 1e-37f) s = 1e-37f;  // stay normal; loud-but-finite floor
    out[b] = -LN2F * ((float)ell + LOG2F(s));
  }
}

extern "C" void kernel_launch(void* const* d_in, const int* in_sizes, int n_in,
                              void* d_out, int out_size, void* d_ws,
                              size_t ws_size, hipStream_t stream) {
  const int* yt = (const int*)d_in[0];
  const float* yp = (const float*)d_in[1];
  float* out = (float*)d_out;
  const int B = in_sizes[0] / LL;  // 128
  uint* ET = (uint*)d_ws;                                       // 33.55 MB
  float* EB = (float*)((char*)d_ws + (size_t)B * 64 * TT * 4);  // +512 KB
  hipLaunchKernelGGL(prep_kernel, dim3(B * 128), dim3(512), 0, stream, yt, yp,
                     ET, EB);
  hipLaunchKernelGGL(scan_kernel, dim3(B), dim3(64), 0, stream, yt, ET, EB,
                     out);
}